// Round 16
// baseline (589.128 us; speedup 1.0000x reference)
//
#include <hip/hip_runtime.h>

// Problem constants (from reference)
constexpr int kNGene = 40000;
constexpr int kNGoid = 10000;
constexpr int kN     = 50000;
constexpr int kE     = 800000;
constexpr int kInDim = 1280;
constexpr int kH1    = 256;
constexpr int kH2    = 128;
constexpr int kOut   = 64;
constexpr int kGDim  = 4096;
constexpr int kD1    = 1024;

typedef short bf16x8 __attribute__((ext_vector_type(8)));
typedef float f32x4  __attribute__((ext_vector_type(4)));
typedef float f32x16 __attribute__((ext_vector_type(16)));

static __device__ __forceinline__ short f2bf(float f) {
  union { float f; unsigned u; } v; v.f = f;
  unsigned r = v.u + 0x7FFF + ((v.u >> 16) & 1);   // RNE; inputs are finite
  return (short)(r >> 16);
}
static __device__ __forceinline__ float bf2f(short s) {
  union { unsigned u; float f; } v;
  v.u = ((unsigned)(unsigned short)s) << 16;
  return v.f;
}
// async global->LDS, 16B/lane; LDS dest = base + lane*16 (wave-linear).
static __device__ __forceinline__ void gld16(const void* g, void* l) {
  __builtin_amdgcn_global_load_lds(
      (const __attribute__((address_space(1))) void*)g,
      (__attribute__((address_space(3))) void*)l, 16, 0, 0);
}
// counted-vmcnt pipeline barrier
template <int N>
static __device__ __forceinline__ void wait_barrier() {
  if constexpr (N == 0)      asm volatile("s_waitcnt vmcnt(0)" ::: "memory");
  else if constexpr (N == 3) asm volatile("s_waitcnt vmcnt(3)" ::: "memory");
  else                       asm volatile("s_waitcnt vmcnt(4)" ::: "memory");
  __builtin_amdgcn_s_barrier();
  asm volatile("" ::: "memory");
}

// ---------------- fused prep: goidx cvt + 7 weight transposes + deg init ----
constexpr int kCvtBlocks   = 20000;  // 10000*4096/8/256
constexpr int kTransBlocks = 6088;   // 4096+1280+320+320+32+32+8
constexpr int kInitBlocks  = 196;    // ceil(50000/256)

__global__ __launch_bounds__(256)
void k_prep(const float* __restrict__ goid_x, short* __restrict__ goidx_bf,
            const float* __restrict__ Wd1, short* __restrict__ Wd1t,
            const float* __restrict__ Wd2, short* __restrict__ Wd2t,
            const float* __restrict__ W1,  short* __restrict__ W1t,
            const float* __restrict__ Wp1, short* __restrict__ Wp1t,
            const float* __restrict__ W2,  short* __restrict__ W2t,
            const float* __restrict__ Wp2, short* __restrict__ Wp2t,
            const float* __restrict__ Wf,  short* __restrict__ Wft,
            float* __restrict__ deg, int* __restrict__ gcount)
{
  __shared__ float t[32][33];
  int b = blockIdx.x;
  if (b < kCvtBlocks) {                       // goid_x -> bf16
    int idx = b * 256 + threadIdx.x;          // chunk of 8
    int r = idx >> 9;
    int c = (idx & 511) << 3;
    const float* sp = goid_x + (size_t)r * kGDim + c;
    float4 v0 = *reinterpret_cast<const float4*>(sp);
    float4 v1 = *reinterpret_cast<const float4*>(sp + 4);
    bf16x8 o;
    o[0]=f2bf(v0.x); o[1]=f2bf(v0.y); o[2]=f2bf(v0.z); o[3]=f2bf(v0.w);
    o[4]=f2bf(v1.x); o[5]=f2bf(v1.y); o[6]=f2bf(v1.z); o[7]=f2bf(v1.w);
    *reinterpret_cast<bf16x8*>(goidx_bf + (size_t)r * kGDim + c) = o;
    return;
  }
  if (b >= kCvtBlocks + kTransBlocks) {       // deg init
    int i = (b - kCvtBlocks - kTransBlocks) * 256 + threadIdx.x;
    if (i < kN) deg[i] = 1.0f;
    if (i == 0) *gcount = 0;
    return;
  }
  int b2 = b - kCvtBlocks;
  const float* W; short* Wt; int K, N, bi;
  if (b2 < 4096)      { W = Wd1; Wt = Wd1t; K = 4096; N = 1024; bi = b2; }
  else if (b2 < 5376) { W = Wd2; Wt = Wd2t; K = 1024; N = 1280; bi = b2 - 4096; }
  else if (b2 < 5696) { W = W1;  Wt = W1t;  K = 1280; N = 256;  bi = b2 - 5376; }
  else if (b2 < 6016) { W = Wp1; Wt = Wp1t; K = 1280; N = 256;  bi = b2 - 5696; }
  else if (b2 < 6048) { W = W2;  Wt = W2t;  K = 256;  N = 128;  bi = b2 - 6016; }
  else if (b2 < 6080) { W = Wp2; Wt = Wp2t; K = 256;  N = 128;  bi = b2 - 6048; }
  else                { W = Wf;  Wt = Wft;  K = 128;  N = 64;   bi = b2 - 6080; }
  int nbx = N >> 5;
  int n0 = (bi % nbx) * 32, k0 = (bi / nbx) * 32;
  int tx = threadIdx.x & 31, ty = threadIdx.x >> 5;
#pragma unroll
  for (int p = 0; p < 4; ++p)
    t[ty + 8 * p][tx] = W[(size_t)(k0 + ty + 8 * p) * N + n0 + tx];
  __syncthreads();
#pragma unroll
  for (int p = 0; p < 4; ++p)
    Wt[(size_t)(n0 + ty + 8 * p) * K + k0 + tx] = f2bf(t[tx][ty + 8 * p]);
}

// ---------------- CSR device pieces (512-thread blocks) ----------------
static __device__ void dev_hist(const int* __restrict__ ei, float* __restrict__ deg,
                                int bid) {
  int e = bid * 512 + threadIdx.x;
  if (e < kE) atomicAdd(&deg[ei[kE + e]], 1.0f);
}
static __device__ void dev_rowassign(const float* __restrict__ deg,
                                     int* __restrict__ rowstart,
                                     int* __restrict__ cursor,
                                     int* __restrict__ gcount, int bid) {
  int i = bid * 512 + threadIdx.x;
  int lane = threadIdx.x & 63;
  int c = (i < kNGene) ? ((int)deg[i] - 1) : 0;
  int incl = c;
#pragma unroll
  for (int off = 1; off < 64; off <<= 1) {
    int t = __shfl_up(incl, off, 64);
    if (lane >= off) incl += t;
  }
  int total = __shfl(incl, 63, 64);
  int base = 0;
  if (lane == 63) base = atomicAdd(gcount, total);
  base = __shfl(base, 63, 64);
  if (i < kNGene) {
    int s = base + incl - c;
    rowstart[i] = s;
    cursor[i] = s;
  }
}
static __device__ void dev_fill(const int* __restrict__ ei, const float* __restrict__ deg,
                                int* __restrict__ cursor, int2* __restrict__ edges,
                                int bid) {
  int e = bid * 512 + threadIdx.x;
  if (e >= kE) return;
  int dst = ei[kE + e];
  if (dst >= kNGene) return;
  int src = ei[e];
  int pos = atomicAdd(&cursor[dst], 1);
  float nrm = rsqrtf(deg[src] * deg[dst]);
  edges[pos] = make_int2(src, __float_as_int(nrm));
}

// ---------------- gather: half-wave 2-edge scheme, bf16 in/out --------------
template <int F>
__global__ __launch_bounds__(256)
void k_gather2(const short* __restrict__ xw, const float* __restrict__ deg,
               const int* __restrict__ rowstart, const int2* __restrict__ edges,
               const float* __restrict__ bias, short* __restrict__ h) {
  constexpr int VEC = F / 32;            // 8 (F=256) or 4 (F=128)
  int row = (blockIdx.x * blockDim.x + threadIdx.x) >> 6;
  int lane = threadIdx.x & 63;
  int half = lane >> 5, lp = lane & 31;
  if (row >= kNGene) return;
  float dg = deg[row];
  float inv = 1.0f / dg;
  float acc[VEC] = {};
  if (half == 0) {                       // self-loop in half 0 only
    const short* xr = xw + (size_t)row * F + lp * VEC;
    if constexpr (VEC == 8) {
      bf16x8 s = *reinterpret_cast<const bf16x8*>(xr);
#pragma unroll
      for (int v = 0; v < 8; ++v) acc[v] = bf2f(s[v]) * inv;
    } else {
      short4 s = *reinterpret_cast<const short4*>(xr);
      acc[0] = bf2f(s.x) * inv; acc[1] = bf2f(s.y) * inv;
      acc[2] = bf2f(s.z) * inv; acc[3] = bf2f(s.w) * inv;
    }
  }
  int e0 = rowstart[row];
  int n = (int)dg - 1;
  for (int e = half; e < n; e += 2) {
    int2 p = edges[e0 + e];
    float nrm = __int_as_float(p.y);
    const short* xs = xw + (size_t)p.x * F + lp * VEC;
    if constexpr (VEC == 8) {
      bf16x8 s = *reinterpret_cast<const bf16x8*>(xs);
#pragma unroll
      for (int v = 0; v < 8; ++v) acc[v] += bf2f(s[v]) * nrm;
    } else {
      short4 s = *reinterpret_cast<const short4*>(xs);
      acc[0] += bf2f(s.x) * nrm; acc[1] += bf2f(s.y) * nrm;
      acc[2] += bf2f(s.z) * nrm; acc[3] += bf2f(s.w) * nrm;
    }
  }
  // merge halves
#pragma unroll
  for (int v = 0; v < VEC; ++v) acc[v] += __shfl_xor(acc[v], 32, 64);
  if (half == 0) {
    short o[VEC];
#pragma unroll
    for (int v = 0; v < VEC; ++v)
      o[v] = f2bf(fmaxf(acc[v] + bias[lp * VEC + v], 0.f));
    short* hp = h + (size_t)row * F + lp * VEC;
    if constexpr (VEC == 8)
      *reinterpret_cast<bf16x8*>(hp) = *reinterpret_cast<bf16x8*>(o);
    else
      *reinterpret_cast<short4*>(hp) = *reinterpret_cast<short4*>(o);
  }
}

// ---------------- dev: bf16 GEMM 128x256, 8 waves, 2-buf, 32x32x16 MFMA -----
// LDS linear [row][32 shorts]; A-frag: row=lane&31, k=(lane>>5)*8; B same.
// C/D: col=lane&31, row=(reg&3)+8*(reg>>2)+4*(lane>>5)  [m74/m101 verified].
template <int RELU, int OBF>
static __device__ void dev_wide(const short* __restrict__ A, int lda,
                                const short* __restrict__ Bt,
                                const float* __restrict__ bias,
                                void* __restrict__ Cv, int ldc,
                                int M, int K, int b0, int nbx, int nwg,
                                short* As, short* Bs)
{
  const int tid  = threadIdx.x;
  const int lane = tid & 63;
  const int wid  = tid >> 6;        // 0..7
  const int wr = wid >> 2, wc = wid & 3;
  // bijective XCD swizzle (m204)
  int qq = nwg >> 3, rr = nwg & 7, xcd = b0 & 7, j = b0 >> 3;
  int swz = ((xcd < rr) ? xcd * (qq + 1) : rr * (qq + 1) + (xcd - rr) * qq) + j;
  const int row0 = (swz / nbx) * 128;
  const int col0 = (swz % nbx) * 256;
  const int l31 = lane & 31, lh = lane >> 5;
  const int srow = lane >> 2, schunk = lane & 3;   // linear staging

  f32x16 acc00 = {}, acc01 = {}, acc10 = {}, acc11 = {};

  auto stage = [&](int buf, int k0) {
#pragma unroll
    for (int q = 0; q < 3; ++q) {
      int s = wid * 3 + q;
      if (s < 8) {
        int grow = row0 + s * 16 + srow;
        if (grow >= M) grow = M - 1;
        gld16(A + (size_t)grow * lda + k0 + schunk * 8, As + buf * 4096 + s * 512);
      } else {
        int gcol = col0 + (s - 8) * 16 + srow;
        gld16(Bt + (size_t)gcol * K + k0 + schunk * 8, Bs + buf * 8192 + (s - 8) * 512);
      }
    }
  };

  stage(0, 0);
  __syncthreads();
  int cur = 0;
  for (int k0 = 0; k0 < K; k0 += 32) {
    if (k0 + 32 < K) stage(cur ^ 1, k0 + 32);
    bf16x8 a0[2], a1[2], b0v[2], b1v[2];   // [kc]
#pragma unroll
    for (int kc = 0; kc < 2; ++kc) {
      a0[kc] = *reinterpret_cast<bf16x8*>(As + cur * 4096 + (wr * 64 + 0  + l31) * 32 + kc * 16 + lh * 8);
      a1[kc] = *reinterpret_cast<bf16x8*>(As + cur * 4096 + (wr * 64 + 32 + l31) * 32 + kc * 16 + lh * 8);
      b0v[kc] = *reinterpret_cast<bf16x8*>(Bs + cur * 8192 + (wc * 64 + 0  + l31) * 32 + kc * 16 + lh * 8);
      b1v[kc] = *reinterpret_cast<bf16x8*>(Bs + cur * 8192 + (wc * 64 + 32 + l31) * 32 + kc * 16 + lh * 8);
    }
#pragma unroll
    for (int kc = 0; kc < 2; ++kc) {
      acc00 = __builtin_amdgcn_mfma_f32_32x32x16_bf16(a0[kc], b0v[kc], acc00, 0, 0, 0);
      acc01 = __builtin_amdgcn_mfma_f32_32x32x16_bf16(a0[kc], b1v[kc], acc01, 0, 0, 0);
      acc10 = __builtin_amdgcn_mfma_f32_32x32x16_bf16(a1[kc], b0v[kc], acc10, 0, 0, 0);
      acc11 = __builtin_amdgcn_mfma_f32_32x32x16_bf16(a1[kc], b1v[kc], acc11, 0, 0, 0);
    }
    __syncthreads();
    cur ^= 1;
  }

  // epilogue: 2x2 tiles of 32x32
#pragma unroll
  for (int n = 0; n < 2; ++n) {
    int col = col0 + wc * 64 + n * 32 + l31;
    float bv = bias ? bias[col] : 0.f;
#pragma unroll
    for (int m = 0; m < 2; ++m) {
      const f32x16& av = (m == 0) ? (n == 0 ? acc00 : acc01)
                                  : (n == 0 ? acc10 : acc11);
#pragma unroll
      for (int reg = 0; reg < 16; ++reg) {
        int r = row0 + wr * 64 + m * 32 + (reg & 3) + 8 * (reg >> 2) + 4 * lh;
        if (r < M) {
          float v = av[reg] + bv;
          if (RELU) v = fmaxf(v, 0.f);
          size_t idx = (size_t)r * ldc + col;
          if constexpr (OBF) ((short*)Cv)[idx] = f2bf(v);
          else               ((float*)Cv)[idx] = v;
        }
      }
    }
  }
}

// ---------------- dev: gene xw1, fp32-A, 128x256, 8 waves, 2-buf ------------
static __device__ void dev_gene(const float* __restrict__ A, int lda,
                                const short* __restrict__ Bt,
                                short* __restrict__ C, int M, int K,
                                int bx, short* As, short* Bs)
{
  const int tid  = threadIdx.x;
  const int lane = tid & 63;
  const int wid  = tid >> 6;
  const int wr = wid >> 2, wc = wid & 3;
  const int row0 = bx * 128;
  const int l15 = lane & 15, l4 = lane >> 4;
  const int sr = tid >> 2, sc = tid & 3;
  const int srow = lane >> 2;
  const int schunk = (lane & 3) ^ ((lane >> 3) & 3);
  const int rslot8 = (l4 ^ ((l15 >> 1) & 3)) * 8;

  f32x4 acc[4][4] = {};

  auto stageB = [&](int buf, int k0) {
#pragma unroll
    for (int q = 0; q < 2; ++q) {
      int seg = wid * 2 + q;
      int gcol = seg * 16 + srow;
      gld16(Bt + (size_t)gcol * K + k0 + schunk * 8, Bs + buf * 8192 + seg * 512);
    }
  };
  auto stageA = [&](int buf, int k0) {
    int grow = row0 + sr;
    float4 v0 = make_float4(0.f,0.f,0.f,0.f), v1 = v0;
    if (grow < M) {
      const float* ap = A + (size_t)grow * lda + k0 + sc * 8;
      v0 = *reinterpret_cast<const float4*>(ap);
      v1 = *reinterpret_cast<const float4*>(ap + 4);
    }
    bf16x8 t;
    t[0]=f2bf(v0.x); t[1]=f2bf(v0.y); t[2]=f2bf(v0.z); t[3]=f2bf(v0.w);
    t[4]=f2bf(v1.x); t[5]=f2bf(v1.y); t[6]=f2bf(v1.z); t[7]=f2bf(v1.w);
    *reinterpret_cast<bf16x8*>(As + buf * 5120 + sr * 40 + sc * 8) = t;
  };

  stageB(0, 0); stageA(0, 0);
  __syncthreads();
  int cur = 0;
  for (int k0 = 0; k0 < K; k0 += 32) {
    if (k0 + 32 < K) { stageB(cur ^ 1, k0 + 32); stageA(cur ^ 1, k0 + 32); }
    bf16x8 af[4], bfr[4];
#pragma unroll
    for (int m = 0; m < 4; ++m)
      af[m] = *reinterpret_cast<bf16x8*>(As + cur * 5120 + (wr * 64 + m * 16 + l15) * 40 + l4 * 8);
#pragma unroll
    for (int n = 0; n < 4; ++n)
      bfr[n] = *reinterpret_cast<bf16x8*>(Bs + cur * 8192 + (wc * 64 + n * 16 + l15) * 32 + rslot8);
#pragma unroll
    for (int m = 0; m < 4; ++m)
#pragma unroll
      for (int n = 0; n < 4; ++n)
        acc[m][n] = __builtin_amdgcn_mfma_f32_16x16x32_bf16(af[m], bfr[n], acc[m][n], 0, 0, 0);
    __syncthreads();
    cur ^= 1;
  }

#pragma unroll
  for (int n = 0; n < 4; ++n) {
    int col = wc * 64 + n * 16 + l15;
#pragma unroll
    for (int m = 0; m < 4; ++m) {
      int rb = row0 + wr * 64 + m * 16 + l4 * 4;
#pragma unroll
      for (int e = 0; e < 4; ++e) {
        int r = rb + e;
        if (r < M) C[(size_t)r * 256 + col] = f2bf(acc[m][n][e]);
      }
    }
  }
}

// ---------------- dev: combined goid GEMM (128x256, 8 waves, 2-buf) ---------
static __device__ void dev_combo(const short* __restrict__ A, int lda,
                                 const short* __restrict__ Bt,
                                 const float* __restrict__ bp1,
                                 short* __restrict__ X1, short* __restrict__ H1,
                                 int M, int K, int bx, int by,
                                 short* As, short* Bs)
{
  const int tid  = threadIdx.x;
  const int lane = tid & 63;
  const int wid  = tid >> 6;
  const int wr = wid >> 2, wc = wid & 3;
  const int row0 = by * 128;
  const int col0 = bx * 256;
  const int l15 = lane & 15, l4 = lane >> 4;
  const int srow = lane >> 2;
  const int schunk = (lane & 3) ^ ((lane >> 3) & 3);
  const int rslot8 = (l4 ^ ((l15 >> 1) & 3)) * 8;

  f32x4 acc[4][4] = {};

  auto stage = [&](int buf, int k0) {
#pragma unroll
    for (int q = 0; q < 3; ++q) {
      int s = wid * 3 + q;
      if (s < 8) {
        int grow = row0 + s * 16 + srow;
        if (grow >= M) grow = M - 1;
        gld16(A + (size_t)grow * lda + k0 + schunk * 8, As + buf * 4096 + s * 512);
      } else {
        int gcol = col0 + (s - 8) * 16 + srow;
        gld16(Bt + (size_t)gcol * K + k0 + schunk * 8, Bs + buf * 8192 + (s - 8) * 512);
      }
    }
  };

  stage(0, 0);
  __syncthreads();
  int cur = 0;
  for (int k0 = 0; k0 < K; k0 += 32) {
    if (k0 + 32 < K) stage(cur ^ 1, k0 + 32);
    bf16x8 af[4], bfr[4];
#pragma unroll
    for (int m = 0; m < 4; ++m)
      af[m] = *reinterpret_cast<bf16x8*>(As + cur * 4096 + (wr * 64 + m * 16 + l15) * 32 + rslot8);
#pragma unroll
    for (int n = 0; n < 4; ++n)
      bfr[n] = *reinterpret_cast<bf16x8*>(Bs + cur * 8192 + (wc * 64 + n * 16 + l15) * 32 + rslot8);
#pragma unroll
    for (int m = 0; m < 4; ++m)
#pragma unroll
      for (int n = 0; n < 4; ++n)
        acc[m][n] = __builtin_amdgcn_mfma_f32_16x16x32_bf16(af[m], bfr[n], acc[m][n], 0, 0, 0);
    __syncthreads();
    cur ^= 1;
  }

  const int is_p1 = (col0 >= 256);
  short* dstp = is_p1 ? H1 : X1;
#pragma unroll
  for (int n = 0; n < 4; ++n) {
    int cl = wc * 64 + n * 16 + l15;
    float bv = is_p1 ? bp1[cl] : 0.f;
#pragma unroll
    for (int m = 0; m < 4; ++m) {
      int rb = row0 + wr * 64 + m * 16 + l4 * 4;
#pragma unroll
      for (int e = 0; e < 4; ++e) {
        int r = rb + e;
        if (r < M) dstp[(size_t)r * 256 + cl] = f2bf(acc[m][n][e] + bv);
      }
    }
  }
}

// ---------------- dev: bf16 GEMM 128x128, 3-buf counted pipeline ------------
template <int RELU, int OBF>
static __device__ void dev_bf16a(const short* __restrict__ A, int lda,
                                 const short* __restrict__ Bt,
                                 const float* __restrict__ bias,
                                 void* __restrict__ Cv, int ldc,
                                 int M, int K, int bx, int by,
                                 short* As, short* Bs)
{
  const int tid  = threadIdx.x;
  const int lane = tid & 63;
  const int wid  = tid >> 6;
  const int wr = wid >> 1, wc = wid & 1;
  const int row0 = by * 128;
  const int col0 = bx * 128;
  const int l15 = lane & 15, l4 = lane >> 4;
  const int srow = lane >> 2;
  const int schunk = (lane & 3) ^ ((lane >> 3) & 3);
  const int rslot8 = (l4 ^ ((l15 >> 1) & 3)) * 8;

  f32x4 acc[4][4] = {};

  auto stage = [&](int buf, int k0) {   // 4 gld16 per wave
#pragma unroll
    for (int q = 0; q < 2; ++q) {
      int seg = wid * 2 + q;
      int r = seg * 16 + srow;
      int grow = row0 + r;
      if (grow >= M) grow = M - 1;
      gld16(A + (size_t)grow * lda + k0 + schunk * 8, As + buf * 4096 + seg * 512);
      int gcol = col0 + r;
      gld16(Bt + (size_t)gcol * K + k0 + schunk * 8, Bs + buf * 4096 + seg * 512);
    }
  };

  const int nt = K >> 5;
  stage(0, 0);
  if (nt > 1) { stage(1, 32); wait_barrier<4>(); }
  else        { wait_barrier<0>(); }

  for (int t = 0; t < nt; ++t) {
    if (t + 2 < nt) stage((t + 2) % 3, (t + 2) * 32);
    const int cur = t % 3;
    bf16x8 af[4], bfr[4];
#pragma unroll
    for (int m = 0; m < 4; ++m)
      af[m] = *reinterpret_cast<bf16x8*>(As + cur * 4096 + (wr * 64 + m * 16 + l15) * 32 + rslot8);
#pragma unroll
    for (int n = 0; n < 4; ++n)
      bfr[n] = *reinterpret_cast<bf16x8*>(Bs + cur * 4096 + (wc * 64 + n * 16 + l15) * 32 + rslot8);
#pragma unroll
    for (int m = 0; m < 4; ++m)
#pragma unroll
      for (int n = 0; n < 4; ++n)
        acc[m][n] = __builtin_amdgcn_mfma_f32_16x16x32_bf16(af[m], bfr[n], acc[m][n], 0, 0, 0);
    if (t + 1 < nt) {
      if (t + 2 < nt) wait_barrier<4>(); else wait_barrier<0>();
    }
  }

#pragma unroll
  for (int n = 0; n < 4; ++n) {
    int col = col0 + wc * 64 + n * 16 + l15;
    float bv = bias ? bias[col] : 0.f;
#pragma unroll
    for (int m = 0; m < 4; ++m) {
      int rb = row0 + wr * 64 + m * 16 + l4 * 4;
#pragma unroll
      for (int e = 0; e < 4; ++e) {
        int r = rb + e;
        if (r < M) {
          float v = acc[m][n][e] + bv;
          if (RELU) v = fmaxf(v, 0.f);
          size_t idx = (size_t)r * ldc + col;
          if constexpr (OBF) ((short*)Cv)[idx] = f2bf(v);
          else               ((float*)Cv)[idx] = v;
        }
      }
    }
  }
}

// ---------------- merged super-kernels ----------------
constexpr int kWd1Blocks  = 316;   // (10000/128=79 rows)x(1024/256=4 cols)
constexpr int kGeneBlocks = 313;   // 40000/128
constexpr int kHistBlocks = 1563;  // ceil(800000/512)
constexpr int kWd2Blocks  = 395;   // 79 x (1280/256=5)
constexpr int kRowBlocks  = 79;    // ceil(40000/512)
constexpr int kComboBlocks = 158;  // 79 x 2
constexpr int kXw2Blocks  = 391;   // ceil(50000/128)
constexpr int kWp2Blocks  = 79;    // ceil(10000/128)

__global__ __launch_bounds__(512)
void k_big1(const short* goidx_bf, const short* Wd1t, const float* bd1, short* h1tmp_bf,
            const float* gene_x, const short* W1t, short* xw1_bf,
            const int* ei, float* deg)
{
  extern __shared__ short smem[];
  int b = blockIdx.x;
  if (b < kWd1Blocks) {
    dev_wide<1,1>(goidx_bf, kGDim, Wd1t, bd1, h1tmp_bf, kD1, kNGoid, kGDim,
                  b, 4, kWd1Blocks, smem, smem + 2 * 4096);
  } else if (b < kWd1Blocks + kGeneBlocks) {
    dev_gene(gene_x, kGDim, W1t, xw1_bf, kNGene, kInDim,
             b - kWd1Blocks, smem, smem + 2 * 5120);
  } else {
    dev_hist(ei, deg, b - kWd1Blocks - kGeneBlocks);
  }
}

__global__ __launch_bounds__(512)
void k_big2(const short* h1tmp_bf, const short* Wd2t, const float* bd2, short* goidt_bf,
            const float* deg, int* rowstart, int* cursor, int* gcount)
{
  extern __shared__ short smem[];
  int b = blockIdx.x;
  if (b < kWd2Blocks) {
    dev_wide<1,1>(h1tmp_bf, kD1, Wd2t, bd2, goidt_bf, kInDim, kNGoid, kD1,
                  b, 5, kWd2Blocks, smem, smem + 2 * 4096);
  } else {
    dev_rowassign(deg, rowstart, cursor, gcount, b - kWd2Blocks);
  }
}

__global__ __launch_bounds__(512)
void k_big3(const short* goidt_bf, const short* Wcomb, const float* bp1,
            short* X1, short* H1,
            const int* ei, const float* deg, int* cursor, int2* edges)
{
  extern __shared__ short smem[];
  int b = blockIdx.x;
  if (b < kComboBlocks) {
    dev_combo(goidt_bf, kInDim, Wcomb, bp1, X1, H1, kNGoid, kInDim,
              b & 1, b >> 1, smem, smem + 2 * 4096);
  } else {
    dev_fill(ei, deg, cursor, edges, b - kComboBlocks);
  }
}

__global__ __launch_bounds__(256)
void k_xwp(const short* h1bf, const short* W2t, short* xw2_bf,
           const short* h1goid, const short* Wp2t, const float* bp2, short* h2goid)
{
  extern __shared__ short smem[];
  int b = blockIdx.x;
  if (b < kXw2Blocks) {
    dev_bf16a<0,1>(h1bf, kH1, W2t, nullptr, xw2_bf, kH2, kN, kH1,
                   0, b, smem, smem + 3 * 4096);
  } else {
    dev_bf16a<0,1>(h1goid, kH1, Wp2t, bp2, h2goid, kH2, kNGoid, kH1,
                   0, b - kXw2Blocks, smem, smem + 3 * 4096);
  }
}

// ---------------- out layer: h2bf[M][128] @ Wft[64][128] + bf -> out fp32 ----
__global__ __launch_bounds__(256)
void k_gemm_out(const short* __restrict__ A,      // h2bf, lda=128
                const short* __restrict__ Bt,     // Wft [64][128]
                const float* __restrict__ bias,
                float* __restrict__ C,            // [M][64]
                int M)
{
  __shared__ __align__(16) short As[2][256 * 32];
  __shared__ __align__(16) short Bs[2][64 * 32];
  const int tid  = threadIdx.x;
  const int lane = tid & 63;
  const int wid  = tid >> 6;
  const int row0 = blockIdx.x * 256;
  const int l15 = lane & 15, l4 = lane >> 4;
  const int srow = lane >> 2;
  const int schunk = (lane & 3) ^ ((lane >> 3) & 3);
  const int rslot8 = (l4 ^ ((l15 >> 1) & 3)) * 8;

  f32x4 acc[4][4] = {};

  auto stage = [&](int buf, int k0) {
#pragma unroll
    for (int q = 0; q < 4; ++q) {
      int seg = wid * 4 + q;
      int grow = row0 + seg * 16 + srow;
      if (grow >= M) grow = M - 1;
      gld16(A + (size_t)grow * 128 + k0 + schunk * 8, &As[buf][seg * 512]);
    }
    int gcol = wid * 16 + srow;
    gld16(Bt + (size_t)gcol * 128 + k0 + schunk * 8, &Bs[buf][wid * 512]);
  };

  stage(0, 0);
  __syncthreads();
  int cur = 0;
  for (int k0 = 0; k0 < 128; k0 += 32) {
    if (k0 + 32 < 128) stage(cur ^ 1, k0 + 32);
    bf16x8 af[4], bfr[4];
#pragma unroll
    for (int m = 0; m < 4; ++m)
      af[m] = *reinterpret_cast<bf16x8*>(&As[cur][(wid * 64 + m * 16 + l15) * 32 + rslot8]);
#pragma unroll
    for (int n = 0; n < 4; ++n)
      bfr[n] = *reinterpret_cast<bf16x8*>(&Bs[cur][(n * 16 + l15) * 32 + rslot8]);
#pragma unroll
    for (int m = 0; m < 4; ++m)
#pragma unroll
      for (int n = 0; n < 4; ++n)
        acc[m][n] = __builtin_amdgcn_mfma_f32_16x16x32_bf16(af[m], bfr[n], acc[m][n], 0, 0, 0);
    __syncthreads();
    cur ^= 1;
  }

#pragma unroll
  for (int n = 0; n < 4; ++n) {
    int col = n * 16 + l15;
    float bv = bias[col];
#pragma unroll
    for (int m = 0; m < 4; ++m) {
      int rb = row0 + wid * 64 + m * 16 + l4 * 4;
#pragma unroll
      for (int e = 0; e < 4; ++e) {
        int r = rb + e;
        if (r < M) C[(size_t)r * 64 + col] = acc[m][n][e] + bv;
      }
    }
  }
}

extern "C" void kernel_launch(void* const* d_in, const int* in_sizes, int n_in,
                              void* d_out, int out_size, void* d_ws, size_t ws_size,
                              hipStream_t stream) {
  const float* x   = (const float*)d_in[0];
  const int*   ei  = (const int*)d_in[1];
  const float* Wd1 = (const float*)d_in[3];
  const float* bd1 = (const float*)d_in[4];
  const float* Wd2 = (const float*)d_in[5];
  const float* bd2 = (const float*)d_in[6];
  const float* W1  = (const float*)d_in[7];
  const float* b1  = (const float*)d_in[8];
  const float* W2  = (const float*)d_in[9];
  const float* b2  = (const float*)d_in[10];
  const float* Wp1 = (const float*)d_in[11];
  const float* bp1 = (const float*)d_in[12];
  const float* Wp2 = (const float*)d_in[13];
  const float* bp2 = (const float*)d_in[14];
  const float* Wf  = (const float*)d_in[15];
  const float* bf_ = (const float*)d_in[16];
  float* out = (float*)d_out;
  float* ws  = (float*)d_ws;

  // workspace (float offsets), non-overlapping, 16B-aligned
  short* goidx_bf = (short*)(ws + 0);          // 10000 x 4096 bf16
  short* goidt_bf = (short*)(ws + 20480000);   // 10000 x 1280 bf16
  short* h1tmp_bf = (short*)(ws + 26880000);   // 10000 x 1024 bf16
  short* Wd1t = (short*)(ws + 32000000);       // 1024 x 4096
  short* Wd2t = (short*)(ws + 34097152);       // 1280 x 1024
  short* W1t  = (short*)(ws + 34752512);       //  256 x 1280 \ contiguous ->
  short* Wp1t = (short*)(ws + 34916352);       //  256 x 1280 / Wcomb[512][1280]
  short* W2t  = (short*)(ws + 35080192);       //  128 x 256
  short* xw1_bf = (short*)(ws + 35100000);     // 50000 x 256 bf16
  short* h1bf   = (short*)(ws + 41500000);     // 50000 x 256 bf16
  short* xw2_bf = (short*)(ws + 50460000);     // 50000 x 128 bf16
  short* h2bf   = (short*)(ws + 53660000);     // 50000 x 128 bf16
  float* deg    = ws + 60060000;               // 50,000
  int*   rowstart = (int*)(ws + 60150016);     // 40,000
  int*   cursor   = (int*)(ws + 60190016);     // 40,000
  int2*  edges    = (int2*)(ws + 60230016);    // 800,000 x 8B
  int*   gcount   = (int*)(ws + 61830016);     // 1
  short* Wp2t = (short*)(ws + 61830032);       // 128 x 256
  short* Wft  = (short*)(ws + 61846416);       //  64 x 128

  const float* gene_x = x;                          // rows 0..39999, lda=4096
  const float* goid_x = x + (size_t)kNGene * kGDim; // rows 40000..49999

  // 0) fused prep: goidx cvt + 7 weight transposes + deg init
  k_prep<<<kCvtBlocks + kTransBlocks + kInitBlocks, 256, 0, stream>>>(
      goid_x, goidx_bf, Wd1, Wd1t, Wd2, Wd2t, W1, W1t, Wp1, Wp1t,
      W2, W2t, Wp2, Wp2t, Wf, Wft, deg, gcount);

  // 1) big1: Wd1 GEMM (32x32 MFMA) || gene xw1 GEMM || degree histogram
  k_big1<<<kWd1Blocks + kGeneBlocks + kHistBlocks, 512, 53248, stream>>>(
      goidx_bf, Wd1t, bd1, h1tmp_bf, gene_x, W1t, xw1_bf, ei, deg);

  // 2) big2: Wd2 GEMM (32x32 MFMA) || rowassign
  k_big2<<<kWd2Blocks + kRowBlocks, 512, 49152, stream>>>(
      h1tmp_bf, Wd2t, bd2, goidt_bf, deg, rowstart, cursor, gcount);

  // 3) big3: combo GEMM (xw1 goid rows + h1 goid rows) || edge fill
  k_big3<<<kComboBlocks + kHistBlocks, 512, 49152, stream>>>(
      goidt_bf, W1t /*=Wcomb[512][1280]*/, bp1,
      xw1_bf + (size_t)kNGene * kH1, h1bf + (size_t)kNGene * kH1,
      ei, deg, cursor, edges);

  // 4) conv1: gather (half-wave 2-edge) -> h1 bf16 gene rows
  k_gather2<kH1><<<(kNGene * 64 + 255) / 256, 256, 0, stream>>>(
      xw1_bf, deg, rowstart, edges, b1, h1bf);

  // 5) xw2 GEMM || Wp2 GEMM
  k_xwp<<<kXw2Blocks + kWp2Blocks, 256, 49152, stream>>>(
      h1bf, W2t, xw2_bf,
      h1bf + (size_t)kNGene * kH1, Wp2t, bp2, h2bf + (size_t)kNGene * kH2);

  // 6) conv2: gather (half-wave 2-edge) -> h2 bf16 gene rows
  k_gather2<kH2><<<(kNGene * 64 + 255) / 256, 256, 0, stream>>>(
      xw2_bf, deg, rowstart, edges, b2, h2bf);

  // 7) out = h2 @ Wf + bf (bf16 MFMA, 256x64 tile)
  k_gemm_out<<<(kN + 255) / 256, 256, 0, stream>>>(h2bf, Wft, bf_, out, kN);
}

// Round 17
// 571.074 us; speedup vs baseline: 1.0316x; 1.0316x over previous
//
#include <hip/hip_runtime.h>

// Problem constants (from reference)
constexpr int kNGene = 40000;
constexpr int kNGoid = 10000;
constexpr int kN     = 50000;
constexpr int kE     = 800000;
constexpr int kInDim = 1280;
constexpr int kH1    = 256;
constexpr int kH2    = 128;
constexpr int kOut   = 64;
constexpr int kGDim  = 4096;
constexpr int kD1    = 1024;

typedef short bf16x8 __attribute__((ext_vector_type(8)));
typedef float f32x4  __attribute__((ext_vector_type(4)));

static __device__ __forceinline__ short f2bf(float f) {
  union { float f; unsigned u; } v; v.f = f;
  unsigned r = v.u + 0x7FFF + ((v.u >> 16) & 1);   // RNE; inputs are finite
  return (short)(r >> 16);
}
static __device__ __forceinline__ float bf2f(short s) {
  union { unsigned u; float f; } v;
  v.u = ((unsigned)(unsigned short)s) << 16;
  return v.f;
}
// async global->LDS, 16B/lane; LDS dest = base + lane*16 (wave-linear).
static __device__ __forceinline__ void gld16(const void* g, void* l) {
  __builtin_amdgcn_global_load_lds(
      (const __attribute__((address_space(1))) void*)g,
      (__attribute__((address_space(3))) void*)l, 16, 0, 0);
}
// counted-vmcnt pipeline barrier
template <int N>
static __device__ __forceinline__ void wait_barrier() {
  if constexpr (N == 0)      asm volatile("s_waitcnt vmcnt(0)" ::: "memory");
  else if constexpr (N == 3) asm volatile("s_waitcnt vmcnt(3)" ::: "memory");
  else                       asm volatile("s_waitcnt vmcnt(4)" ::: "memory");
  __builtin_amdgcn_s_barrier();
  asm volatile("" ::: "memory");
}

// ---------------- fused prep: goidx cvt + 7 weight transposes + deg init ----
constexpr int kCvtBlocks   = 20000;  // 10000*4096/8/256
constexpr int kTransBlocks = 6088;   // 4096+1280+320+320+32+32+8
constexpr int kInitBlocks  = 196;    // ceil(50000/256)

__global__ __launch_bounds__(256)
void k_prep(const float* __restrict__ goid_x, short* __restrict__ goidx_bf,
            const float* __restrict__ Wd1, short* __restrict__ Wd1t,
            const float* __restrict__ Wd2, short* __restrict__ Wd2t,
            const float* __restrict__ W1,  short* __restrict__ W1t,
            const float* __restrict__ Wp1, short* __restrict__ Wp1t,
            const float* __restrict__ W2,  short* __restrict__ W2t,
            const float* __restrict__ Wp2, short* __restrict__ Wp2t,
            const float* __restrict__ Wf,  short* __restrict__ Wft,
            float* __restrict__ deg, int* __restrict__ gcount)
{
  __shared__ float t[32][33];
  int b = blockIdx.x;
  if (b < kCvtBlocks) {                       // goid_x -> bf16
    int idx = b * 256 + threadIdx.x;          // chunk of 8
    int r = idx >> 9;
    int c = (idx & 511) << 3;
    const float* sp = goid_x + (size_t)r * kGDim + c;
    float4 v0 = *reinterpret_cast<const float4*>(sp);
    float4 v1 = *reinterpret_cast<const float4*>(sp + 4);
    bf16x8 o;
    o[0]=f2bf(v0.x); o[1]=f2bf(v0.y); o[2]=f2bf(v0.z); o[3]=f2bf(v0.w);
    o[4]=f2bf(v1.x); o[5]=f2bf(v1.y); o[6]=f2bf(v1.z); o[7]=f2bf(v1.w);
    *reinterpret_cast<bf16x8*>(goidx_bf + (size_t)r * kGDim + c) = o;
    return;
  }
  if (b >= kCvtBlocks + kTransBlocks) {       // deg init
    int i = (b - kCvtBlocks - kTransBlocks) * 256 + threadIdx.x;
    if (i < kN) deg[i] = 1.0f;
    if (i == 0) *gcount = 0;
    return;
  }
  int b2 = b - kCvtBlocks;
  const float* W; short* Wt; int K, N, bi;
  if (b2 < 4096)      { W = Wd1; Wt = Wd1t; K = 4096; N = 1024; bi = b2; }
  else if (b2 < 5376) { W = Wd2; Wt = Wd2t; K = 1024; N = 1280; bi = b2 - 4096; }
  else if (b2 < 5696) { W = W1;  Wt = W1t;  K = 1280; N = 256;  bi = b2 - 5376; }
  else if (b2 < 6016) { W = Wp1; Wt = Wp1t; K = 1280; N = 256;  bi = b2 - 5696; }
  else if (b2 < 6048) { W = W2;  Wt = W2t;  K = 256;  N = 128;  bi = b2 - 6016; }
  else if (b2 < 6080) { W = Wp2; Wt = Wp2t; K = 256;  N = 128;  bi = b2 - 6048; }
  else                { W = Wf;  Wt = Wft;  K = 128;  N = 64;   bi = b2 - 6080; }
  int nbx = N >> 5;
  int n0 = (bi % nbx) * 32, k0 = (bi / nbx) * 32;
  int tx = threadIdx.x & 31, ty = threadIdx.x >> 5;
#pragma unroll
  for (int p = 0; p < 4; ++p)
    t[ty + 8 * p][tx] = W[(size_t)(k0 + ty + 8 * p) * N + n0 + tx];
  __syncthreads();
#pragma unroll
  for (int p = 0; p < 4; ++p)
    Wt[(size_t)(n0 + ty + 8 * p) * K + k0 + tx] = f2bf(t[tx][ty + 8 * p]);
}

// ---------------- CSR device pieces (512-thread blocks) ----------------
static __device__ void dev_hist(const int* __restrict__ ei, float* __restrict__ deg,
                                int bid) {
  int e = bid * 512 + threadIdx.x;
  if (e < kE) atomicAdd(&deg[ei[kE + e]], 1.0f);
}
static __device__ void dev_rowassign(const float* __restrict__ deg,
                                     int* __restrict__ rowstart,
                                     int* __restrict__ cursor,
                                     int* __restrict__ gcount, int bid) {
  int i = bid * 512 + threadIdx.x;
  int lane = threadIdx.x & 63;
  int c = (i < kNGene) ? ((int)deg[i] - 1) : 0;
  int incl = c;
#pragma unroll
  for (int off = 1; off < 64; off <<= 1) {
    int t = __shfl_up(incl, off, 64);
    if (lane >= off) incl += t;
  }
  int total = __shfl(incl, 63, 64);
  int base = 0;
  if (lane == 63) base = atomicAdd(gcount, total);
  base = __shfl(base, 63, 64);
  if (i < kNGene) {
    int s = base + incl - c;
    rowstart[i] = s;
    cursor[i] = s;
  }
}
static __device__ void dev_fill(const int* __restrict__ ei, const float* __restrict__ deg,
                                int* __restrict__ cursor, int2* __restrict__ edges,
                                int bid) {
  int e = bid * 512 + threadIdx.x;
  if (e >= kE) return;
  int dst = ei[kE + e];
  if (dst >= kNGene) return;
  int src = ei[e];
  int pos = atomicAdd(&cursor[dst], 1);
  float nrm = rsqrtf(deg[src] * deg[dst]);
  edges[pos] = make_int2(src, __float_as_int(nrm));
}

// ---------------- gather: half-wave 2-edge scheme, bf16 in/out --------------
template <int F>
__global__ __launch_bounds__(256)
void k_gather2(const short* __restrict__ xw, const float* __restrict__ deg,
               const int* __restrict__ rowstart, const int2* __restrict__ edges,
               const float* __restrict__ bias, short* __restrict__ h) {
  constexpr int VEC = F / 32;            // 8 (F=256) or 4 (F=128)
  int row = (blockIdx.x * blockDim.x + threadIdx.x) >> 6;
  int lane = threadIdx.x & 63;
  int half = lane >> 5, lp = lane & 31;
  if (row >= kNGene) return;
  float dg = deg[row];
  float inv = 1.0f / dg;
  float acc[VEC] = {};
  if (half == 0) {                       // self-loop in half 0 only
    const short* xr = xw + (size_t)row * F + lp * VEC;
    if constexpr (VEC == 8) {
      bf16x8 s = *reinterpret_cast<const bf16x8*>(xr);
#pragma unroll
      for (int v = 0; v < 8; ++v) acc[v] = bf2f(s[v]) * inv;
    } else {
      short4 s = *reinterpret_cast<const short4*>(xr);
      acc[0] = bf2f(s.x) * inv; acc[1] = bf2f(s.y) * inv;
      acc[2] = bf2f(s.z) * inv; acc[3] = bf2f(s.w) * inv;
    }
  }
  int e0 = rowstart[row];
  int n = (int)dg - 1;
  for (int e = half; e < n; e += 2) {
    int2 p = edges[e0 + e];
    float nrm = __int_as_float(p.y);
    const short* xs = xw + (size_t)p.x * F + lp * VEC;
    if constexpr (VEC == 8) {
      bf16x8 s = *reinterpret_cast<const bf16x8*>(xs);
#pragma unroll
      for (int v = 0; v < 8; ++v) acc[v] += bf2f(s[v]) * nrm;
    } else {
      short4 s = *reinterpret_cast<const short4*>(xs);
      acc[0] += bf2f(s.x) * nrm; acc[1] += bf2f(s.y) * nrm;
      acc[2] += bf2f(s.z) * nrm; acc[3] += bf2f(s.w) * nrm;
    }
  }
  // merge halves
#pragma unroll
  for (int v = 0; v < VEC; ++v) acc[v] += __shfl_xor(acc[v], 32, 64);
  if (half == 0) {
    short o[VEC];
#pragma unroll
    for (int v = 0; v < VEC; ++v)
      o[v] = f2bf(fmaxf(acc[v] + bias[lp * VEC + v], 0.f));
    short* hp = h + (size_t)row * F + lp * VEC;
    if constexpr (VEC == 8)
      *reinterpret_cast<bf16x8*>(hp) = *reinterpret_cast<bf16x8*>(o);
    else
      *reinterpret_cast<short4*>(hp) = *reinterpret_cast<short4*>(o);
  }
}

// ---------------- dev: bf16 GEMM 128x256, 8 waves, 2-buf, swizzled LDS ------
template <int RELU, int OBF>
static __device__ void dev_wide(const short* __restrict__ A, int lda,
                                const short* __restrict__ Bt,
                                const float* __restrict__ bias,
                                void* __restrict__ Cv, int ldc,
                                int M, int K, int b0, int nbx, int nwg,
                                short* As, short* Bs)
{
  const int tid  = threadIdx.x;
  const int lane = tid & 63;
  const int wid  = tid >> 6;        // 0..7
  const int wr = wid >> 2, wc = wid & 3;
  // bijective XCD swizzle (m204)
  int qq = nwg >> 3, rr = nwg & 7, xcd = b0 & 7, j = b0 >> 3;
  int swz = ((xcd < rr) ? xcd * (qq + 1) : rr * (qq + 1) + (xcd - rr) * qq) + j;
  const int row0 = (swz / nbx) * 128;
  const int col0 = (swz % nbx) * 256;
  const int l15 = lane & 15, l4 = lane >> 4;
  const int srow = lane >> 2;
  const int schunk = (lane & 3) ^ ((lane >> 3) & 3);
  const int rslot8 = (l4 ^ ((l15 >> 1) & 3)) * 8;

  f32x4 acc[4][4] = {};

  auto stage = [&](int buf, int k0) {
#pragma unroll
    for (int q = 0; q < 3; ++q) {
      int s = wid * 3 + q;
      if (s < 8) {
        int grow = row0 + s * 16 + srow;
        if (grow >= M) grow = M - 1;
        gld16(A + (size_t)grow * lda + k0 + schunk * 8, As + buf * 4096 + s * 512);
      } else {
        int gcol = col0 + (s - 8) * 16 + srow;
        gld16(Bt + (size_t)gcol * K + k0 + schunk * 8, Bs + buf * 8192 + (s - 8) * 512);
      }
    }
  };

  stage(0, 0);
  __syncthreads();
  int cur = 0;
  for (int k0 = 0; k0 < K; k0 += 32) {
    if (k0 + 32 < K) stage(cur ^ 1, k0 + 32);
    bf16x8 af[4], bfr[4];
#pragma unroll
    for (int m = 0; m < 4; ++m)
      af[m] = *reinterpret_cast<bf16x8*>(As + cur * 4096 + (wr * 64 + m * 16 + l15) * 32 + rslot8);
#pragma unroll
    for (int n = 0; n < 4; ++n)
      bfr[n] = *reinterpret_cast<bf16x8*>(Bs + cur * 8192 + (wc * 64 + n * 16 + l15) * 32 + rslot8);
#pragma unroll
    for (int m = 0; m < 4; ++m)
#pragma unroll
      for (int n = 0; n < 4; ++n)
        acc[m][n] = __builtin_amdgcn_mfma_f32_16x16x32_bf16(af[m], bfr[n], acc[m][n], 0, 0, 0);
    __syncthreads();
    cur ^= 1;
  }

#pragma unroll
  for (int n = 0; n < 4; ++n) {
    int col = col0 + wc * 64 + n * 16 + l15;
    float bv = bias ? bias[col] : 0.f;
#pragma unroll
    for (int m = 0; m < 4; ++m) {
      int rb = row0 + wr * 64 + m * 16 + l4 * 4;
#pragma unroll
      for (int e = 0; e < 4; ++e) {
        int r = rb + e;
        if (r < M) {
          float v = acc[m][n][e] + bv;
          if (RELU) v = fmaxf(v, 0.f);
          size_t idx = (size_t)r * ldc + col;
          if constexpr (OBF) ((short*)Cv)[idx] = f2bf(v);
          else               ((float*)Cv)[idx] = v;
        }
      }
    }
  }
}

// ---------------- dev: gene xw1, fp32-A, 128x256, 8 waves, 2-buf ------------
static __device__ void dev_gene(const float* __restrict__ A, int lda,
                                const short* __restrict__ Bt,
                                short* __restrict__ C, int M, int K,
                                int bx, short* As, short* Bs)
{
  const int tid  = threadIdx.x;
  const int lane = tid & 63;
  const int wid  = tid >> 6;
  const int wr = wid >> 2, wc = wid & 3;
  const int row0 = bx * 128;
  const int l15 = lane & 15, l4 = lane >> 4;
  const int sr = tid >> 2, sc = tid & 3;
  const int srow = lane >> 2;
  const int schunk = (lane & 3) ^ ((lane >> 3) & 3);
  const int rslot8 = (l4 ^ ((l15 >> 1) & 3)) * 8;

  f32x4 acc[4][4] = {};

  auto stageB = [&](int buf, int k0) {
#pragma unroll
    for (int q = 0; q < 2; ++q) {
      int seg = wid * 2 + q;
      int gcol = seg * 16 + srow;
      gld16(Bt + (size_t)gcol * K + k0 + schunk * 8, Bs + buf * 8192 + seg * 512);
    }
  };
  auto stageA = [&](int buf, int k0) {
    int grow = row0 + sr;
    float4 v0 = make_float4(0.f,0.f,0.f,0.f), v1 = v0;
    if (grow < M) {
      const float* ap = A + (size_t)grow * lda + k0 + sc * 8;
      v0 = *reinterpret_cast<const float4*>(ap);
      v1 = *reinterpret_cast<const float4*>(ap + 4);
    }
    bf16x8 t;
    t[0]=f2bf(v0.x); t[1]=f2bf(v0.y); t[2]=f2bf(v0.z); t[3]=f2bf(v0.w);
    t[4]=f2bf(v1.x); t[5]=f2bf(v1.y); t[6]=f2bf(v1.z); t[7]=f2bf(v1.w);
    *reinterpret_cast<bf16x8*>(As + buf * 5120 + sr * 40 + sc * 8) = t;
  };

  stageB(0, 0); stageA(0, 0);
  __syncthreads();
  int cur = 0;
  for (int k0 = 0; k0 < K; k0 += 32) {
    if (k0 + 32 < K) { stageB(cur ^ 1, k0 + 32); stageA(cur ^ 1, k0 + 32); }
    bf16x8 af[4], bfr[4];
#pragma unroll
    for (int m = 0; m < 4; ++m)
      af[m] = *reinterpret_cast<bf16x8*>(As + cur * 5120 + (wr * 64 + m * 16 + l15) * 40 + l4 * 8);
#pragma unroll
    for (int n = 0; n < 4; ++n)
      bfr[n] = *reinterpret_cast<bf16x8*>(Bs + cur * 8192 + (wc * 64 + n * 16 + l15) * 32 + rslot8);
#pragma unroll
    for (int m = 0; m < 4; ++m)
#pragma unroll
      for (int n = 0; n < 4; ++n)
        acc[m][n] = __builtin_amdgcn_mfma_f32_16x16x32_bf16(af[m], bfr[n], acc[m][n], 0, 0, 0);
    __syncthreads();
    cur ^= 1;
  }

#pragma unroll
  for (int n = 0; n < 4; ++n) {
    int col = wc * 64 + n * 16 + l15;
#pragma unroll
    for (int m = 0; m < 4; ++m) {
      int rb = row0 + wr * 64 + m * 16 + l4 * 4;
#pragma unroll
      for (int e = 0; e < 4; ++e) {
        int r = rb + e;
        if (r < M) C[(size_t)r * 256 + col] = f2bf(acc[m][n][e]);
      }
    }
  }
}

// ---------------- dev: combined goid GEMM (128x256, 8 waves, 2-buf) ---------
static __device__ void dev_combo(const short* __restrict__ A, int lda,
                                 const short* __restrict__ Bt,
                                 const float* __restrict__ bp1,
                                 short* __restrict__ X1, short* __restrict__ H1,
                                 int M, int K, int bx, int by,
                                 short* As, short* Bs)
{
  const int tid  = threadIdx.x;
  const int lane = tid & 63;
  const int wid  = tid >> 6;
  const int wr = wid >> 2, wc = wid & 3;
  const int row0 = by * 128;
  const int col0 = bx * 256;
  const int l15 = lane & 15, l4 = lane >> 4;
  const int srow = lane >> 2;
  const int schunk = (lane & 3) ^ ((lane >> 3) & 3);
  const int rslot8 = (l4 ^ ((l15 >> 1) & 3)) * 8;

  f32x4 acc[4][4] = {};

  auto stage = [&](int buf, int k0) {
#pragma unroll
    for (int q = 0; q < 3; ++q) {
      int s = wid * 3 + q;
      if (s < 8) {
        int grow = row0 + s * 16 + srow;
        if (grow >= M) grow = M - 1;
        gld16(A + (size_t)grow * lda + k0 + schunk * 8, As + buf * 4096 + s * 512);
      } else {
        int gcol = col0 + (s - 8) * 16 + srow;
        gld16(Bt + (size_t)gcol * K + k0 + schunk * 8, Bs + buf * 8192 + (s - 8) * 512);
      }
    }
  };

  stage(0, 0);
  __syncthreads();
  int cur = 0;
  for (int k0 = 0; k0 < K; k0 += 32) {
    if (k0 + 32 < K) stage(cur ^ 1, k0 + 32);
    bf16x8 af[4], bfr[4];
#pragma unroll
    for (int m = 0; m < 4; ++m)
      af[m] = *reinterpret_cast<bf16x8*>(As + cur * 4096 + (wr * 64 + m * 16 + l15) * 32 + rslot8);
#pragma unroll
    for (int n = 0; n < 4; ++n)
      bfr[n] = *reinterpret_cast<bf16x8*>(Bs + cur * 8192 + (wc * 64 + n * 16 + l15) * 32 + rslot8);
#pragma unroll
    for (int m = 0; m < 4; ++m)
#pragma unroll
      for (int n = 0; n < 4; ++n)
        acc[m][n] = __builtin_amdgcn_mfma_f32_16x16x32_bf16(af[m], bfr[n], acc[m][n], 0, 0, 0);
    __syncthreads();
    cur ^= 1;
  }

  const int is_p1 = (col0 >= 256);
  short* dstp = is_p1 ? H1 : X1;
#pragma unroll
  for (int n = 0; n < 4; ++n) {
    int cl = wc * 64 + n * 16 + l15;
    float bv = is_p1 ? bp1[cl] : 0.f;
#pragma unroll
    for (int m = 0; m < 4; ++m) {
      int rb = row0 + wr * 64 + m * 16 + l4 * 4;
#pragma unroll
      for (int e = 0; e < 4; ++e) {
        int r = rb + e;
        if (r < M) dstp[(size_t)r * 256 + cl] = f2bf(acc[m][n][e] + bv);
      }
    }
  }
}

// ---------------- dev: bf16 GEMM 128x128, 3-buf counted pipeline ------------
template <int RELU, int OBF>
static __device__ void dev_bf16a(const short* __restrict__ A, int lda,
                                 const short* __restrict__ Bt,
                                 const float* __restrict__ bias,
                                 void* __restrict__ Cv, int ldc,
                                 int M, int K, int bx, int by,
                                 short* As, short* Bs)
{
  const int tid  = threadIdx.x;
  const int lane = tid & 63;
  const int wid  = tid >> 6;
  const int wr = wid >> 1, wc = wid & 1;
  const int row0 = by * 128;
  const int col0 = bx * 128;
  const int l15 = lane & 15, l4 = lane >> 4;
  const int srow = lane >> 2;
  const int schunk = (lane & 3) ^ ((lane >> 3) & 3);
  const int rslot8 = (l4 ^ ((l15 >> 1) & 3)) * 8;

  f32x4 acc[4][4] = {};

  auto stage = [&](int buf, int k0) {   // 4 gld16 per wave
#pragma unroll
    for (int q = 0; q < 2; ++q) {
      int seg = wid * 2 + q;
      int r = seg * 16 + srow;
      int grow = row0 + r;
      if (grow >= M) grow = M - 1;
      gld16(A + (size_t)grow * lda + k0 + schunk * 8, As + buf * 4096 + seg * 512);
      int gcol = col0 + r;
      gld16(Bt + (size_t)gcol * K + k0 + schunk * 8, Bs + buf * 4096 + seg * 512);
    }
  };

  const int nt = K >> 5;
  stage(0, 0);
  if (nt > 1) { stage(1, 32); wait_barrier<4>(); }
  else        { wait_barrier<0>(); }

  for (int t = 0; t < nt; ++t) {
    if (t + 2 < nt) stage((t + 2) % 3, (t + 2) * 32);
    const int cur = t % 3;
    bf16x8 af[4], bfr[4];
#pragma unroll
    for (int m = 0; m < 4; ++m)
      af[m] = *reinterpret_cast<bf16x8*>(As + cur * 4096 + (wr * 64 + m * 16 + l15) * 32 + rslot8);
#pragma unroll
    for (int n = 0; n < 4; ++n)
      bfr[n] = *reinterpret_cast<bf16x8*>(Bs + cur * 4096 + (wc * 64 + n * 16 + l15) * 32 + rslot8);
#pragma unroll
    for (int m = 0; m < 4; ++m)
#pragma unroll
      for (int n = 0; n < 4; ++n)
        acc[m][n] = __builtin_amdgcn_mfma_f32_16x16x32_bf16(af[m], bfr[n], acc[m][n], 0, 0, 0);
    if (t + 1 < nt) {
      if (t + 2 < nt) wait_barrier<4>(); else wait_barrier<0>();
    }
  }

#pragma unroll
  for (int n = 0; n < 4; ++n) {
    int col = col0 + wc * 64 + n * 16 + l15;
    float bv = bias ? bias[col] : 0.f;
#pragma unroll
    for (int m = 0; m < 4; ++m) {
      int rb = row0 + wr * 64 + m * 16 + l4 * 4;
#pragma unroll
      for (int e = 0; e < 4; ++e) {
        int r = rb + e;
        if (r < M) {
          float v = acc[m][n][e] + bv;
          if (RELU) v = fmaxf(v, 0.f);
          size_t idx = (size_t)r * ldc + col;
          if constexpr (OBF) ((short*)Cv)[idx] = f2bf(v);
          else               ((float*)Cv)[idx] = v;
        }
      }
    }
  }
}

// ---------------- merged super-kernels ----------------
constexpr int kWd1Blocks  = 316;   // (10000/128=79 rows)x(1024/256=4 cols)
constexpr int kGeneBlocks = 313;   // 40000/128
constexpr int kHistBlocks = 1563;  // ceil(800000/512)
constexpr int kWd2Blocks  = 395;   // 79 x (1280/256=5)
constexpr int kRowBlocks  = 79;    // ceil(40000/512)
constexpr int kComboBlocks = 158;  // 79 x 2
constexpr int kXw2Blocks  = 391;   // ceil(50000/128)
constexpr int kWp2Blocks  = 79;    // ceil(10000/128)

__global__ __launch_bounds__(512)
void k_big1(const short* goidx_bf, const short* Wd1t, const float* bd1, short* h1tmp_bf,
            const float* gene_x, const short* W1t, short* xw1_bf,
            const int* ei, float* deg)
{
  extern __shared__ short smem[];
  int b = blockIdx.x;
  if (b < kWd1Blocks) {
    dev_wide<1,1>(goidx_bf, kGDim, Wd1t, bd1, h1tmp_bf, kD1, kNGoid, kGDim,
                  b, 4, kWd1Blocks, smem, smem + 2 * 4096);
  } else if (b < kWd1Blocks + kGeneBlocks) {
    dev_gene(gene_x, kGDim, W1t, xw1_bf, kNGene, kInDim,
             b - kWd1Blocks, smem, smem + 2 * 5120);
  } else {
    dev_hist(ei, deg, b - kWd1Blocks - kGeneBlocks);
  }
}

__global__ __launch_bounds__(512)
void k_big2(const short* h1tmp_bf, const short* Wd2t, const float* bd2, short* goidt_bf,
            const float* deg, int* rowstart, int* cursor, int* gcount)
{
  extern __shared__ short smem[];
  int b = blockIdx.x;
  if (b < kWd2Blocks) {
    dev_wide<1,1>(h1tmp_bf, kD1, Wd2t, bd2, goidt_bf, kInDim, kNGoid, kD1,
                  b, 5, kWd2Blocks, smem, smem + 2 * 4096);
  } else {
    dev_rowassign(deg, rowstart, cursor, gcount, b - kWd2Blocks);
  }
}

__global__ __launch_bounds__(512)
void k_big3(const short* goidt_bf, const short* Wcomb, const float* bp1,
            short* X1, short* H1,
            const int* ei, const float* deg, int* cursor, int2* edges)
{
  extern __shared__ short smem[];
  int b = blockIdx.x;
  if (b < kComboBlocks) {
    dev_combo(goidt_bf, kInDim, Wcomb, bp1, X1, H1, kNGoid, kInDim,
              b & 1, b >> 1, smem, smem + 2 * 4096);
  } else {
    dev_fill(ei, deg, cursor, edges, b - kComboBlocks);
  }
}

__global__ __launch_bounds__(256)
void k_xwp(const short* h1bf, const short* W2t, short* xw2_bf,
           const short* h1goid, const short* Wp2t, const float* bp2, short* h2goid)
{
  extern __shared__ short smem[];
  int b = blockIdx.x;
  if (b < kXw2Blocks) {
    dev_bf16a<0,1>(h1bf, kH1, W2t, nullptr, xw2_bf, kH2, kN, kH1,
                   0, b, smem, smem + 3 * 4096);
  } else {
    dev_bf16a<0,1>(h1goid, kH1, Wp2t, bp2, h2goid, kH2, kNGoid, kH1,
                   0, b - kXw2Blocks, smem, smem + 3 * 4096);
  }
}

// ---------------- out layer: h2bf[M][128] @ Wft[64][128] + bf -> out fp32 ----
__global__ __launch_bounds__(256)
void k_gemm_out(const short* __restrict__ A,      // h2bf, lda=128
                const short* __restrict__ Bt,     // Wft [64][128]
                const float* __restrict__ bias,
                float* __restrict__ C,            // [M][64]
                int M)
{
  __shared__ __align__(16) short As[2][256 * 32];
  __shared__ __align__(16) short Bs[2][64 * 32];
  const int tid  = threadIdx.x;
  const int lane = tid & 63;
  const int wid  = tid >> 6;
  const int row0 = blockIdx.x * 256;
  const int l15 = lane & 15, l4 = lane >> 4;
  const int srow = lane >> 2;
  const int schunk = (lane & 3) ^ ((lane >> 3) & 3);
  const int rslot8 = (l4 ^ ((l15 >> 1) & 3)) * 8;

  f32x4 acc[4][4] = {};

  auto stage = [&](int buf, int k0) {
#pragma unroll
    for (int q = 0; q < 4; ++q) {
      int seg = wid * 4 + q;
      int grow = row0 + seg * 16 + srow;
      if (grow >= M) grow = M - 1;
      gld16(A + (size_t)grow * 128 + k0 + schunk * 8, &As[buf][seg * 512]);
    }
    int gcol = wid * 16 + srow;
    gld16(Bt + (size_t)gcol * 128 + k0 + schunk * 8, &Bs[buf][wid * 512]);
  };

  stage(0, 0);
  __syncthreads();
  int cur = 0;
  for (int k0 = 0; k0 < 128; k0 += 32) {
    if (k0 + 32 < 128) stage(cur ^ 1, k0 + 32);
    bf16x8 af[4], bfr[4];
#pragma unroll
    for (int m = 0; m < 4; ++m)
      af[m] = *reinterpret_cast<bf16x8*>(&As[cur][(wid * 64 + m * 16 + l15) * 32 + rslot8]);
#pragma unroll
    for (int n = 0; n < 4; ++n)
      bfr[n] = *reinterpret_cast<bf16x8*>(&Bs[cur][(n * 16 + l15) * 32 + rslot8]);
#pragma unroll
    for (int m = 0; m < 4; ++m)
#pragma unroll
      for (int n = 0; n < 4; ++n)
        acc[m][n] = __builtin_amdgcn_mfma_f32_16x16x32_bf16(af[m], bfr[n], acc[m][n], 0, 0, 0);
    __syncthreads();
    cur ^= 1;
  }

#pragma unroll
  for (int n = 0; n < 4; ++n) {
    int col = n * 16 + l15;
    float bv = bias[col];
#pragma unroll
    for (int m = 0; m < 4; ++m) {
      int rb = row0 + wid * 64 + m * 16 + l4 * 4;
#pragma unroll
      for (int e = 0; e < 4; ++e) {
        int r = rb + e;
        if (r < M) C[(size_t)r * 64 + col] = acc[m][n][e] + bv;
      }
    }
  }
}

extern "C" void kernel_launch(void* const* d_in, const int* in_sizes, int n_in,
                              void* d_out, int out_size, void* d_ws, size_t ws_size,
                              hipStream_t stream) {
  const float* x   = (const float*)d_in[0];
  const int*   ei  = (const int*)d_in[1];
  const float* Wd1 = (const float*)d_in[3];
  const float* bd1 = (const float*)d_in[4];
  const float* Wd2 = (const float*)d_in[5];
  const float* bd2 = (const float*)d_in[6];
  const float* W1  = (const float*)d_in[7];
  const float* b1  = (const float*)d_in[8];
  const float* W2  = (const float*)d_in[9];
  const float* b2  = (const float*)d_in[10];
  const float* Wp1 = (const float*)d_in[11];
  const float* bp1 = (const float*)d_in[12];
  const float* Wp2 = (const float*)d_in[13];
  const float* bp2 = (const float*)d_in[14];
  const float* Wf  = (const float*)d_in[15];
  const float* bf_ = (const float*)d_in[16];
  float* out = (float*)d_out;
  float* ws  = (float*)d_ws;

  // workspace (float offsets), non-overlapping, 16B-aligned
  short* goidx_bf = (short*)(ws + 0);          // 10000 x 4096 bf16
  short* goidt_bf = (short*)(ws + 20480000);   // 10000 x 1280 bf16
  short* h1tmp_bf = (short*)(ws + 26880000);   // 10000 x 1024 bf16
  short* Wd1t = (short*)(ws + 32000000);       // 1024 x 4096
  short* Wd2t = (short*)(ws + 34097152);       // 1280 x 1024
  short* W1t  = (short*)(ws + 34752512);       //  256 x 1280 \ contiguous ->
  short* Wp1t = (short*)(ws + 34916352);       //  256 x 1280 / Wcomb[512][1280]
  short* W2t  = (short*)(ws + 35080192);       //  128 x 256
  short* xw1_bf = (short*)(ws + 35100000);     // 50000 x 256 bf16
  short* h1bf   = (short*)(ws + 41500000);     // 50000 x 256 bf16
  short* xw2_bf = (short*)(ws + 50460000);     // 50000 x 128 bf16
  short* h2bf   = (short*)(ws + 53660000);     // 50000 x 128 bf16
  float* deg    = ws + 60060000;               // 50,000
  int*   rowstart = (int*)(ws + 60150016);     // 40,000
  int*   cursor   = (int*)(ws + 60190016);     // 40,000
  int2*  edges    = (int2*)(ws + 60230016);    // 800,000 x 8B
  int*   gcount   = (int*)(ws + 61830016);     // 1
  short* Wp2t = (short*)(ws + 61830032);       // 128 x 256
  short* Wft  = (short*)(ws + 61846416);       //  64 x 128

  const float* gene_x = x;                          // rows 0..39999, lda=4096
  const float* goid_x = x + (size_t)kNGene * kGDim; // rows 40000..49999

  // 0) fused prep: goidx cvt + 7 weight transposes + deg init
  k_prep<<<kCvtBlocks + kTransBlocks + kInitBlocks, 256, 0, stream>>>(
      goid_x, goidx_bf, Wd1, Wd1t, Wd2, Wd2t, W1, W1t, Wp1, Wp1t,
      W2, W2t, Wp2, Wp2t, Wf, Wft, deg, gcount);

  // 1) big1: Wd1 GEMM || gene xw1 GEMM || degree histogram
  k_big1<<<kWd1Blocks + kGeneBlocks + kHistBlocks, 512, 53248, stream>>>(
      goidx_bf, Wd1t, bd1, h1tmp_bf, gene_x, W1t, xw1_bf, ei, deg);

  // 2) big2: Wd2 GEMM || rowassign
  k_big2<<<kWd2Blocks + kRowBlocks, 512, 49152, stream>>>(
      h1tmp_bf, Wd2t, bd2, goidt_bf, deg, rowstart, cursor, gcount);

  // 3) big3: combo GEMM (xw1 goid rows + h1 goid rows) || edge fill
  k_big3<<<kComboBlocks + kHistBlocks, 512, 49152, stream>>>(
      goidt_bf, W1t /*=Wcomb[512][1280]*/, bp1,
      xw1_bf + (size_t)kNGene * kH1, h1bf + (size_t)kNGene * kH1,
      ei, deg, cursor, edges);

  // 4) conv1: gather (half-wave 2-edge) -> h1 bf16 gene rows
  k_gather2<kH1><<<(kNGene * 64 + 255) / 256, 256, 0, stream>>>(
      xw1_bf, deg, rowstart, edges, b1, h1bf);

  // 5) xw2 GEMM || Wp2 GEMM
  k_xwp<<<kXw2Blocks + kWp2Blocks, 256, 49152, stream>>>(
      h1bf, W2t, xw2_bf,
      h1bf + (size_t)kNGene * kH1, Wp2t, bp2, h2bf + (size_t)kNGene * kH2);

  // 6) conv2: gather (half-wave 2-edge) -> h2 bf16 gene rows
  k_gather2<kH2><<<(kNGene * 64 + 255) / 256, 256, 0, stream>>>(
      xw2_bf, deg, rowstart, edges, b2, h2bf);

  // 7) out = h2 @ Wf + bf (bf16 MFMA, 256x64 tile)
  k_gemm_out<<<(kN + 255) / 256, 256, 0, stream>>>(h2bf, Wft, bf_, out, kN);
}